// Round 7
// baseline (242.230 us; speedup 1.0000x reference)
//
#include <hip/hip_runtime.h>
#include <math.h>
#include <stdint.h>

#define M_TOTAL 16384
#define DDIM    4096
#define EXP     64

typedef __attribute__((ext_vector_type(8)))  short bf16x8;
typedef __attribute__((ext_vector_type(16))) float f32x16;

__device__ inline uint32_t fbits(float f){ union{float f;uint32_t u;}c; c.f=f; return c.u; }
__device__ inline float    bitsf(uint32_t u){ union{uint32_t u;float f;}c; c.u=u; return c.f; }
__device__ inline bf16x8   asfrag(uint4 t){ return __builtin_bit_cast(bf16x8, t); }

// ---------------------------------------------------------------------------
// W pre-pack: split w/nw into 3 bf16 planes (truncation split, exact to 2^-24)
// stored in MFMA-B-fragment-linear order:
//   word index = (((s*256 + ktile)*2 + nt)*3 + pl)*256 + lane*4 + j
//   lane = (e&31) + 32*((k>>3)&1), word j holds k-elems 2j,2j+1
// ---------------------------------------------------------------------------
__global__ __launch_bounds__(256) void wpack_prep(
    const float* __restrict__ w, const float* __restrict__ nw,
    uint32_t* __restrict__ wpack)
{
    const int t = blockIdx.x * 256 + threadIdx.x;     // 786432 words total
    const int jw   = t & 3;
    const int lane = (t >> 2) & 63;
    const int rest = t >> 8;                          // ((s*256+kt)*2+nt)*3+pl
    const int pl   = rest % 3;
    const int r2   = rest / 3;
    const int nt   = r2 & 1;
    const int kt   = (r2 >> 1) & 255;
    const int s    = r2 >> 9;

    const int k0 = kt * 16 + (lane >> 5) * 8 + 2 * jw;
    const int e  = nt * 32 + (lane & 31);
    const float* __restrict__ src = s ? nw : w;
    float f0 = src[(size_t)k0 * EXP + e];
    float f1 = src[(size_t)(k0 + 1) * EXP + e];
    uint32_t u0 = fbits(f0), u1 = fbits(f1);
    for (int l = 0; l < pl; ++l) {                    // peel to level pl
        f0 -= bitsf(u0 & 0xFFFF0000u);
        f1 -= bitsf(u1 & 0xFFFF0000u);
        u0 = fbits(f0); u1 = fbits(f1);
    }
    wpack[t] = (u0 >> 16) | (u1 & 0xFFFF0000u);       // [lo=elem2j, hi=elem2j+1]
}

// ---------------------------------------------------------------------------
// MFMA GEMM: part[kp][row][e] = sum over k-plane of (x@w + noise@nw)
// BM=64; A staged ONCE per 256-k chunk (1 KB contiguous per row -> full DRAM
// efficiency); wave = one (mt,nt) 32x32 quadrant; W fragments global->reg
// (L2-resident wpack). NO barriers / LDS writes inside the k-loop.
// ---------------------------------------------------------------------------
template<int KSPLIT>
__global__ __launch_bounds__(256, 2) void router_mfma4(
    const float* __restrict__ x, const float* __restrict__ noise,
    const uint32_t* __restrict__ wpack, float* __restrict__ part)
{
    constexpr int KRANGE = DDIM / KSPLIT;   // k per plane
    constexpr int NCH    = KRANGE / 256;    // 256-k chunks per slice

    __shared__ float Al[64 * 256];          // 64 KB: [row][k], 16B-slot swizzled

    const int tid  = threadIdx.x;
    const int w_   = tid >> 6;
    const int lane = tid & 63;
    const int l31  = lane & 31;
    const int kh   = lane >> 5;             // k-half of the fragment
    const int mt   = w_ >> 1;               // wave quadrant: rows mt*32..+31
    const int nt   = w_ & 1;                //                experts nt*32..+31

    const int rowBase = blockIdx.x * 64;
    const int kp      = blockIdx.y;

    f32x16 acc, macc;
#pragma unroll
    for (int i = 0; i < 16; ++i) { acc[i] = 0.f; macc[i] = 0.f; }

    const int row = mt * 32 + l31;          // this lane's A row (fragment layout)
    const int rs  = row & 7;                // read-side slot swizzle

    for (int s = 0; s < 2; ++s) {
        const float* __restrict__ base = s ? noise : x;
        for (int c = 0; c < NCH; ++c) {
            __syncthreads();                // everyone done reading previous Al
            // ---- stage 64 rows x 256 k: 1 KB contiguous per row; source slot
            //      pre-swizzled (involution) so transpose-reads are conflict-light
            const int kAbs = kp * KRANGE + c * 256;
#pragma unroll
            for (int i = 0; i < 16; ++i) {
                const int sr = i * 4 + w_;
                const int sl = lane ^ (sr & 7);
                const float* src = base + (size_t)(rowBase + sr) * DDIM + kAbs + sl * 4;
                __builtin_amdgcn_global_load_lds(
                    (const __attribute__((address_space(1))) uint32_t*)src,
                    (__attribute__((address_space(3))) uint32_t*)(&Al[sr * 256 + lane * 4]),
                    16, 0, 0);
            }
            __syncthreads();                // staged (barrier drains vmcnt)

            const int kt0 = kp * (KRANGE / 16) + c * 16;
            const uint32_t* __restrict__ wp =
                wpack + ((((size_t)s * 256 + kt0) * 2 + nt) * 3) * 256 + lane * 4;

            // 1-deep W register prefetch; no LDS, no barriers in this loop
            uint4 wq0 = *(const uint4*)(wp);
            uint4 wq1 = *(const uint4*)(wp + 256);
            uint4 wq2 = *(const uint4*)(wp + 512);

#pragma unroll 4
            for (int v = 0; v < 16; ++v) {
                uint4 wn0, wn1, wn2;
                if (v + 1 < 16) {
                    const uint32_t* np = wp + (size_t)(v + 1) * 1536;
                    wn0 = *(const uint4*)(np);
                    wn1 = *(const uint4*)(np + 256);
                    wn2 = *(const uint4*)(np + 512);
                }

                // A fragment: two swizzled 16B slots of this row
                const int s0 = (v * 4 + kh * 2) ^ rs;
                const int s1 = (v * 4 + kh * 2 + 1) ^ rs;
                const float4 a0 = *(const float4*)&Al[row * 256 + s0 * 4];
                const float4 a1 = *(const float4*)&Al[row * 256 + s1 * 4];

                // split to 3 bf16 fragments (truncation split, exact to 2^-24)
                uint32_t fa1[4], fa2[4], fa3[4];
                const float in[8] = { a0.x, a0.y, a0.z, a0.w, a1.x, a1.y, a1.z, a1.w };
#pragma unroll
                for (int j = 0; j < 4; ++j) {
                    const float a = in[2 * j], b = in[2 * j + 1];
                    const uint32_t ha = fbits(a) & 0xFFFF0000u, hb = fbits(b) & 0xFFFF0000u;
                    fa1[j] = (ha >> 16) | hb;
                    const float ra = a - bitsf(ha), rb = b - bitsf(hb);
                    const uint32_t ha2 = fbits(ra) & 0xFFFF0000u, hb2 = fbits(rb) & 0xFFFF0000u;
                    fa2[j] = (ha2 >> 16) | hb2;
                    const float sa = ra - bitsf(ha2), sb = rb - bitsf(hb2);
                    fa3[j] = (fbits(sa) >> 16) | (fbits(sb) & 0xFFFF0000u);
                }
                const bf16x8 a1f = asfrag(*(const uint4*)fa1);
                const bf16x8 a2f = asfrag(*(const uint4*)fa2);
                const bf16x8 a3f = asfrag(*(const uint4*)fa3);
                const bf16x8 b1  = asfrag(wq0);
                const bf16x8 b2  = asfrag(wq1);
                const bf16x8 b3  = asfrag(wq2);

                f32x16 cacc = acc;           // ascending-magnitude product order
                cacc = __builtin_amdgcn_mfma_f32_32x32x16_bf16(a1f, b3, cacc, 0, 0, 0);
                cacc = __builtin_amdgcn_mfma_f32_32x32x16_bf16(a3f, b1, cacc, 0, 0, 0);
                cacc = __builtin_amdgcn_mfma_f32_32x32x16_bf16(a2f, b2, cacc, 0, 0, 0);
                cacc = __builtin_amdgcn_mfma_f32_32x32x16_bf16(a1f, b2, cacc, 0, 0, 0);
                cacc = __builtin_amdgcn_mfma_f32_32x32x16_bf16(a2f, b1, cacc, 0, 0, 0);
                cacc = __builtin_amdgcn_mfma_f32_32x32x16_bf16(a1f, b1, cacc, 0, 0, 0);
                acc = cacc;

                wq0 = wn0; wq1 = wn1; wq2 = wn2;

                // drain 64-k window into fp32 masters (keeps magnitudes small)
                if ((v & 3) == 3) {
#pragma unroll
                    for (int i = 0; i < 16; ++i) { macc[i] += acc[i]; acc[i] = 0.f; }
                }
            }
        }
    }

    // write plane; C/D layout (HW-verified): col=lane&31, row=(r&3)+8*(r>>2)+4*(lane>>5)
    float* __restrict__ out = part + (size_t)blockIdx.y * M_TOTAL * EXP;
#pragma unroll
    for (int r = 0; r < 16; ++r) {
        const int orow = rowBase + mt * 32 + (r & 3) + 8 * (r >> 2) + 4 * kh;
        out[(size_t)orow * EXP + nt * 32 + l31] = macc[r];
    }
}

// one wave per row: logits = f64 sum of planes; top-2 (jax tie-break: lower index
// wins); gates = 2-logit softmax == renormalized full softmax.
__global__ __launch_bounds__(256) void topk_epilogue3(
    const float* __restrict__ part, const int nplanes, float* __restrict__ outv)
{
    const int tid  = threadIdx.x;
    const int lane = tid & 63;
    const int row  = blockIdx.x * 4 + (tid >> 6);

    double sd = 0.0;
    for (int p = 0; p < nplanes; ++p)
        sd += (double)part[((size_t)p * M_TOTAL + row) * EXP + lane];
    const float logit = (float)sd;

    float v = logit; int idx = lane;
#pragma unroll
    for (int off = 32; off >= 1; off >>= 1) {
        const float vo = __shfl_xor(v, off, 64);
        const int   io = __shfl_xor(idx, off, 64);
        if (vo > v || (vo == v && io < idx)) { v = vo; idx = io; }
    }
    const float v1 = v; const int i1 = idx;

    float v2 = (lane == i1) ? -INFINITY : logit; int idx2 = lane;
#pragma unroll
    for (int off = 32; off >= 1; off >>= 1) {
        const float vo = __shfl_xor(v2, off, 64);
        const int   io = __shfl_xor(idx2, off, 64);
        if (vo > v2 || (vo == v2 && io < idx2)) { v2 = vo; idx2 = io; }
    }

    if (lane == 0) {
        const float e2 = expf(v2 - v1);       // <= 1
        const float g1 = 1.0f / (1.0f + e2);
        const float g2 = e2 * g1;
        outv[(size_t)row * 2 + 0] = g1;
        outv[(size_t)row * 2 + 1] = g2;
        outv[(size_t)2 * M_TOTAL + row * 2 + 0] = (float)i1;
        outv[(size_t)2 * M_TOTAL + row * 2 + 1] = (float)idx2;
    }
}

extern "C" void kernel_launch(void* const* d_in, const int* in_sizes, int n_in,
                              void* d_out, int out_size, void* d_ws, size_t ws_size,
                              hipStream_t stream)
{
    const float* x     = (const float*)d_in[0];
    const float* noise = (const float*)d_in[1];
    const float* w     = (const float*)d_in[2];
    const float* nw    = (const float*)d_in[3];
    // d_in[4] = top_k (==2), compile-time assumed

    const size_t plane_bytes = (size_t)M_TOTAL * EXP * sizeof(float);
    const size_t wpack_bytes = (size_t)786432 * 4;
    float* part = (float*)d_ws;

    if (ws_size >= 16 * plane_bytes + wpack_bytes) {
        uint32_t* wpack = (uint32_t*)((char*)d_ws + 16 * plane_bytes);
        wpack_prep<<<3072, 256, 0, stream>>>(w, nw, wpack);
        router_mfma4<16><<<dim3(M_TOTAL / 64, 16), 256, 0, stream>>>(x, noise, wpack, part);
        topk_epilogue3<<<M_TOTAL / 4, 256, 0, stream>>>(part, 16, (float*)d_out);
    } else if (ws_size >= 8 * plane_bytes + wpack_bytes) {
        uint32_t* wpack = (uint32_t*)((char*)d_ws + 8 * plane_bytes);
        wpack_prep<<<3072, 256, 0, stream>>>(w, nw, wpack);
        router_mfma4<8><<<dim3(M_TOTAL / 64, 8), 256, 0, stream>>>(x, noise, wpack, part);
        topk_epilogue3<<<M_TOTAL / 4, 256, 0, stream>>>(part, 8, (float*)d_out);
    } else {
        uint32_t* wpack = (uint32_t*)((char*)d_ws + 4 * plane_bytes);
        wpack_prep<<<3072, 256, 0, stream>>>(w, nw, wpack);
        router_mfma4<4><<<dim3(M_TOTAL / 64, 4), 256, 0, stream>>>(x, noise, wpack, part);
        topk_epilogue3<<<M_TOTAL / 4, 256, 0, stream>>>(part, 4, (float*)d_out);
    }
}

// Round 8
// 223.570 us; speedup vs baseline: 1.0835x; 1.0835x over previous
//
#include <hip/hip_runtime.h>
#include <math.h>
#include <stdint.h>

#define M_TOTAL 16384
#define DDIM    4096
#define EXP     64

typedef __attribute__((ext_vector_type(8)))  short bf16x8;
typedef __attribute__((ext_vector_type(16))) float f32x16;

__device__ inline uint32_t fbits(float f){ union{float f;uint32_t u;}c; c.f=f; return c.u; }
__device__ inline float    bitsf(uint32_t u){ union{uint32_t u;float f;}c; c.u=u; return c.f; }
__device__ inline bf16x8   asfrag(uint4 t){ return __builtin_bit_cast(bf16x8, t); }

// ---------------------------------------------------------------------------
// W pre-pack: split w/nw into 3 bf16 planes (truncation split, exact to 2^-24)
// stored in MFMA-B-fragment-linear order:
//   word index = (((s*256 + kt)*2 + nt)*3 + pl)*256 + lane*4 + j
//   lane = (e&31) + 32*((k>>3)&1), word j holds k-elems 2j,2j+1
// ---------------------------------------------------------------------------
__global__ __launch_bounds__(256) void wpack_prep(
    const float* __restrict__ w, const float* __restrict__ nw,
    uint32_t* __restrict__ wpack)
{
    const int t = blockIdx.x * 256 + threadIdx.x;     // 786432 words total
    const int jw   = t & 3;
    const int lane = (t >> 2) & 63;
    const int rest = t >> 8;                          // ((s*256+kt)*2+nt)*3+pl
    const int pl   = rest % 3;
    const int r2   = rest / 3;
    const int nt   = r2 & 1;
    const int kt   = (r2 >> 1) & 255;
    const int s    = r2 >> 9;

    const int k0 = kt * 16 + (lane >> 5) * 8 + 2 * jw;
    const int e  = nt * 32 + (lane & 31);
    const float* __restrict__ src = s ? nw : w;
    float f0 = src[(size_t)k0 * EXP + e];
    float f1 = src[(size_t)(k0 + 1) * EXP + e];
    uint32_t u0 = fbits(f0), u1 = fbits(f1);
    for (int l = 0; l < pl; ++l) {                    // peel to level pl
        f0 -= bitsf(u0 & 0xFFFF0000u);
        f1 -= bitsf(u1 & 0xFFFF0000u);
        u0 = fbits(f0); u1 = fbits(f1);
    }
    wpack[t] = (u0 >> 16) | (u1 & 0xFFFF0000u);       // [lo=elem2j, hi=elem2j+1]
}

// ---------------------------------------------------------------------------
// MFMA GEMM, zero-sync streaming: part[kp][row][e] = sum_k (x@w + noise@nw)
// Each wave is an independent stream over 32 rows x 64 experts: A global->reg
// (layout-native), W global->reg from L2-resident wpack, 1-deep register
// double-buffer. NO LDS, NO barriers, loads never drain to vmcnt(0).
// ---------------------------------------------------------------------------
template<int KSPLIT>
__global__ __launch_bounds__(256, 3) void router_mfma5(
    const float* __restrict__ x, const float* __restrict__ noise,
    const uint32_t* __restrict__ wpack, float* __restrict__ part)
{
    constexpr int KRANGE = DDIM / KSPLIT;   // k per plane
    constexpr int HALF   = KRANGE / 16;     // ksteps per slice
    constexpr int NU     = 2 * HALF;        // ksteps total (multiple of 4)

    const int tid  = threadIdx.x;
    const int lane = tid & 63;
    const int l31  = lane & 31;
    const int kh   = lane >> 5;             // k-half of the fragment

    const int rowBase = blockIdx.x * 128 + (tid >> 6) * 32;
    const int kp      = blockIdx.y;
    const int ktBase  = kp * HALF;

    const float* __restrict__ xr =
        x     + (size_t)(rowBase + l31) * DDIM + kp * KRANGE + kh * 8;
    const float* __restrict__ nr =
        noise + (size_t)(rowBase + l31) * DDIM + kp * KRANGE + kh * 8;
    const uint32_t* __restrict__ wl = wpack + lane * 4;

    f32x16 acc[2], macc[2];
#pragma unroll
    for (int b = 0; b < 2; ++b)
#pragma unroll
        for (int i = 0; i < 16; ++i) { acc[b][i] = 0.f; macc[b][i] = 0.f; }

    auto aaddr = [&](int u) -> const float* {
        return (u < HALF) ? (xr + u * 16) : (nr + (u - HALF) * 16);
    };
    auto waddr = [&](int u) -> const uint32_t* {
        const int s = (u >= HALF) ? 1 : 0;
        const int v = u - (s ? HALF : 0);
        return wl + (size_t)(s * 256 + ktBase + v) * 1536;
    };

    float4 abuf[2][2];                      // [phase-parity][2 x float4 = 8 k]
    uint4  wbuf[2][6];                      // [phase-parity][nt*3 + plane]

    // ---- prologue: load kstep 0 into parity-0 buffers
    {
        const float* ap = aaddr(0);
        abuf[0][0] = *(const float4*)(ap);
        abuf[0][1] = *(const float4*)(ap + 4);
        const uint32_t* wp = waddr(0);
#pragma unroll
        for (int f = 0; f < 6; ++f) wbuf[0][f] = *(const uint4*)(wp + f * 256);
    }

    for (int uu = 0; uu < NU; uu += 4) {
#pragma unroll
        for (int ph = 0; ph < 4; ++ph) {
            const int u   = uu + ph;
            const int cur = ph & 1;
            const int nxt = cur ^ 1;

            // issue next kstep's loads (register prefetch; counted vmcnt waits)
            if (u + 1 < NU) {
                const float* ap = aaddr(u + 1);
                abuf[nxt][0] = *(const float4*)(ap);
                abuf[nxt][1] = *(const float4*)(ap + 4);
                const uint32_t* wp = waddr(u + 1);
#pragma unroll
                for (int f = 0; f < 6; ++f) wbuf[nxt][f] = *(const uint4*)(wp + f * 256);
            }

            // split A -> 3 bf16 fragments (truncation split, exact to 2^-24)
            uint32_t fa1[4], fa2[4], fa3[4];
            const float in[8] = { abuf[cur][0].x, abuf[cur][0].y,
                                  abuf[cur][0].z, abuf[cur][0].w,
                                  abuf[cur][1].x, abuf[cur][1].y,
                                  abuf[cur][1].z, abuf[cur][1].w };
#pragma unroll
            for (int j = 0; j < 4; ++j) {
                const float a = in[2 * j], b = in[2 * j + 1];
                const uint32_t ha = fbits(a) & 0xFFFF0000u, hb = fbits(b) & 0xFFFF0000u;
                fa1[j] = (ha >> 16) | hb;
                const float ra = a - bitsf(ha), rb = b - bitsf(hb);
                const uint32_t ha2 = fbits(ra) & 0xFFFF0000u, hb2 = fbits(rb) & 0xFFFF0000u;
                fa2[j] = (ha2 >> 16) | hb2;
                const float sa = ra - bitsf(ha2), sb = rb - bitsf(hb2);
                fa3[j] = (fbits(sa) >> 16) | (fbits(sb) & 0xFFFF0000u);
            }
            const bf16x8 a1f = asfrag(*(const uint4*)fa1);
            const bf16x8 a2f = asfrag(*(const uint4*)fa2);
            const bf16x8 a3f = asfrag(*(const uint4*)fa3);

#pragma unroll
            for (int nt = 0; nt < 2; ++nt) {
                const bf16x8 b1 = asfrag(wbuf[cur][nt * 3 + 0]);
                const bf16x8 b2 = asfrag(wbuf[cur][nt * 3 + 1]);
                const bf16x8 b3 = asfrag(wbuf[cur][nt * 3 + 2]);
                f32x16 c = acc[nt];          // ascending-magnitude product order
                c = __builtin_amdgcn_mfma_f32_32x32x16_bf16(a1f, b3, c, 0, 0, 0);
                c = __builtin_amdgcn_mfma_f32_32x32x16_bf16(a3f, b1, c, 0, 0, 0);
                c = __builtin_amdgcn_mfma_f32_32x32x16_bf16(a2f, b2, c, 0, 0, 0);
                c = __builtin_amdgcn_mfma_f32_32x32x16_bf16(a1f, b2, c, 0, 0, 0);
                c = __builtin_amdgcn_mfma_f32_32x32x16_bf16(a2f, b1, c, 0, 0, 0);
                c = __builtin_amdgcn_mfma_f32_32x32x16_bf16(a1f, b1, c, 0, 0, 0);
                acc[nt] = c;
            }

            // drain 64-k window into fp32 masters (compile-time: ph==3)
            if (ph == 3) {
#pragma unroll
                for (int b = 0; b < 2; ++b)
#pragma unroll
                    for (int i = 0; i < 16; ++i) { macc[b][i] += acc[b][i]; acc[b][i] = 0.f; }
            }
        }
    }

    // write plane; C/D layout (HW-verified): col=lane&31, row=(r&3)+8*(r>>2)+4*(lane>>5)
    float* __restrict__ out = part + (size_t)blockIdx.y * M_TOTAL * EXP;
#pragma unroll
    for (int nt = 0; nt < 2; ++nt)
#pragma unroll
        for (int r = 0; r < 16; ++r) {
            const int orow = rowBase + (r & 3) + 8 * (r >> 2) + 4 * kh;
            out[(size_t)orow * EXP + nt * 32 + l31] = macc[nt][r];
        }
}

// one wave per row: logits = f64 sum of planes; top-2 (jax tie-break: lower index
// wins); gates = 2-logit softmax == renormalized full softmax.
__global__ __launch_bounds__(256) void topk_epilogue3(
    const float* __restrict__ part, const int nplanes, float* __restrict__ outv)
{
    const int tid  = threadIdx.x;
    const int lane = tid & 63;
    const int row  = blockIdx.x * 4 + (tid >> 6);

    double sd = 0.0;
    for (int p = 0; p < nplanes; ++p)
        sd += (double)part[((size_t)p * M_TOTAL + row) * EXP + lane];
    const float logit = (float)sd;

    float v = logit; int idx = lane;
#pragma unroll
    for (int off = 32; off >= 1; off >>= 1) {
        const float vo = __shfl_xor(v, off, 64);
        const int   io = __shfl_xor(idx, off, 64);
        if (vo > v || (vo == v && io < idx)) { v = vo; idx = io; }
    }
    const float v1 = v; const int i1 = idx;

    float v2 = (lane == i1) ? -INFINITY : logit; int idx2 = lane;
#pragma unroll
    for (int off = 32; off >= 1; off >>= 1) {
        const float vo = __shfl_xor(v2, off, 64);
        const int   io = __shfl_xor(idx2, off, 64);
        if (vo > v2 || (vo == v2 && io < idx2)) { v2 = vo; idx2 = io; }
    }

    if (lane == 0) {
        const float e2 = expf(v2 - v1);       // <= 1
        const float g1 = 1.0f / (1.0f + e2);
        const float g2 = e2 * g1;
        outv[(size_t)row * 2 + 0] = g1;
        outv[(size_t)row * 2 + 1] = g2;
        outv[(size_t)2 * M_TOTAL + row * 2 + 0] = (float)i1;
        outv[(size_t)2 * M_TOTAL + row * 2 + 1] = (float)idx2;
    }
}

extern "C" void kernel_launch(void* const* d_in, const int* in_sizes, int n_in,
                              void* d_out, int out_size, void* d_ws, size_t ws_size,
                              hipStream_t stream)
{
    const float* x     = (const float*)d_in[0];
    const float* noise = (const float*)d_in[1];
    const float* w     = (const float*)d_in[2];
    const float* nw    = (const float*)d_in[3];
    // d_in[4] = top_k (==2), compile-time assumed

    const size_t plane_bytes = (size_t)M_TOTAL * EXP * sizeof(float);
    const size_t wpack_bytes = (size_t)786432 * 4;
    float* part = (float*)d_ws;

    if (ws_size >= 8 * plane_bytes + wpack_bytes) {
        uint32_t* wpack = (uint32_t*)((char*)d_ws + 8 * plane_bytes);
        wpack_prep<<<3072, 256, 0, stream>>>(w, nw, wpack);
        router_mfma5<8><<<dim3(M_TOTAL / 128, 8), 256, 0, stream>>>(x, noise, wpack, part);
        topk_epilogue3<<<M_TOTAL / 4, 256, 0, stream>>>(part, 8, (float*)d_out);
    } else if (ws_size >= 4 * plane_bytes + wpack_bytes) {
        uint32_t* wpack = (uint32_t*)((char*)d_ws + 4 * plane_bytes);
        wpack_prep<<<3072, 256, 0, stream>>>(w, nw, wpack);
        router_mfma5<4><<<dim3(M_TOTAL / 128, 4), 256, 0, stream>>>(x, noise, wpack, part);
        topk_epilogue3<<<M_TOTAL / 4, 256, 0, stream>>>(part, 4, (float*)d_out);
    } else {
        uint32_t* wpack = (uint32_t*)((char*)d_ws + 2 * plane_bytes);
        wpack_prep<<<3072, 256, 0, stream>>>(w, nw, wpack);
        router_mfma5<2><<<dim3(M_TOTAL / 128, 2), 256, 0, stream>>>(x, noise, wpack, part);
        topk_epilogue3<<<M_TOTAL / 4, 256, 0, stream>>>(part, 2, (float*)d_out);
    }
}

// Round 9
// 217.948 us; speedup vs baseline: 1.1114x; 1.0258x over previous
//
#include <hip/hip_runtime.h>
#include <math.h>
#include <stdint.h>

#define M_TOTAL 16384
#define DDIM    4096
#define EXP     64

typedef __attribute__((ext_vector_type(8)))  short bf16x8;
typedef __attribute__((ext_vector_type(16))) float f32x16;

__device__ inline uint32_t fbits(float f){ union{float f;uint32_t u;}c; c.f=f; return c.u; }
__device__ inline float    bitsf(uint32_t u){ union{uint32_t u;float f;}c; c.u=u; return c.f; }
__device__ inline bf16x8   asfrag(uint4 t){ return __builtin_bit_cast(bf16x8, t); }

// ---------------------------------------------------------------------------
// W pre-pack: split w/nw into 3 bf16 planes (truncation split, exact to 2^-24)
// stored in MFMA-B-fragment-linear order:
//   word index = (((s*256 + kt)*2 + nt)*3 + pl)*256 + lane*4 + j
//   lane = (e&31) + 32*((k>>3)&1), word j holds k-elems 2j,2j+1
// ---------------------------------------------------------------------------
__global__ __launch_bounds__(256) void wpack_prep(
    const float* __restrict__ w, const float* __restrict__ nw,
    uint32_t* __restrict__ wpack)
{
    const int t = blockIdx.x * 256 + threadIdx.x;     // 786432 words total
    const int jw   = t & 3;
    const int lane = (t >> 2) & 63;
    const int rest = t >> 8;                          // ((s*256+kt)*2+nt)*3+pl
    const int pl   = rest % 3;
    const int r2   = rest / 3;
    const int nt   = r2 & 1;
    const int kt   = (r2 >> 1) & 255;
    const int s    = r2 >> 9;

    const int k0 = kt * 16 + (lane >> 5) * 8 + 2 * jw;
    const int e  = nt * 32 + (lane & 31);
    const float* __restrict__ src = s ? nw : w;
    float f0 = src[(size_t)k0 * EXP + e];
    float f1 = src[(size_t)(k0 + 1) * EXP + e];
    uint32_t u0 = fbits(f0), u1 = fbits(f1);
    for (int l = 0; l < pl; ++l) {                    // peel to level pl
        f0 -= bitsf(u0 & 0xFFFF0000u);
        f1 -= bitsf(u1 & 0xFFFF0000u);
        u0 = fbits(f0); u1 = fbits(f1);
    }
    wpack[t] = (u0 >> 16) | (u1 & 0xFFFF0000u);       // [lo=elem2j, hi=elem2j+1]
}

// ---------------------------------------------------------------------------
// MFMA GEMM, wave-private pipeline: part[kp][row][e] = sum_k (x@w + noise@nw)
// Each wave independent: 32 rows x 64 experts. A: global_load_lds into a
// wave-PRIVATE LDS region, 2-deep prefetch, slot-swizzled for even-bank b128
// transpose reads. W: global->reg from L2-resident wpack (only 8 waves/CU ->
// 22% of L2 ceiling). ZERO barriers; one counted s_waitcnt vmcnt(10)/kstep
// (uniform 8 vmem ops per iteration by construction).
// ---------------------------------------------------------------------------
template<int KSPLIT>
__global__ __launch_bounds__(256, 2) void router_mfma6(
    const float* __restrict__ x, const float* __restrict__ noise,
    const uint32_t* __restrict__ wpack, float* __restrict__ part)
{
    constexpr int KRANGE = DDIM / KSPLIT;   // k per plane
    constexpr int VPS    = KRANGE / 16;     // ksteps per slice
    constexpr int NU     = 2 * VPS;         // ksteps total (divisible by 4)

    __shared__ float Al[4][4][512];         // [wave][buf][32 rows x 16 k] = 32 KB

    const int tid  = threadIdx.x;
    const int w_   = tid >> 6;
    const int lane = tid & 63;
    const int l31  = lane & 31;
    const int kh   = lane >> 5;             // k-half of the fragment

    const int rowBase = blockIdx.x * 128 + w_ * 32;
    const int kp      = blockIdx.y;

    // ---- staging source map: instr j covers rows 16j..16j+15, 64 B/row;
    //      source k-quad pre-swizzled (involution s(r) = (r&3)^((r>>2)&3))
    const int r16 = lane >> 2;                               // row-within-16
    const int sw  = ((lane >> 2) & 3) ^ (lane >> 4);         // = s(row)
    const int kq  = (lane & 3) ^ sw;                         // source k-quad

    f32x16 acc[2], macc[2];
#pragma unroll
    for (int b = 0; b < 2; ++b)
#pragma unroll
        for (int i = 0; i < 16; ++i) { acc[b][i] = 0.f; macc[b][i] = 0.f; }

    auto aSrc = [&](int u, int j) -> const float* {
        const int uc = (u < NU) ? u : (NU - 1);              // tail clamp (addr only)
        const int sl = uc / VPS, v = uc % VPS;
        const float* __restrict__ base = sl ? noise : x;
        return base + (size_t)(rowBase + 16 * j + r16) * DDIM
                    + (kp * KRANGE + v * 16 + 4 * kq);
    };
    auto stageA = [&](int u, int b) {                        // 2 gl_lds, 1 KB each
#pragma unroll
        for (int j = 0; j < 2; ++j) {
            __builtin_amdgcn_global_load_lds(
                (const __attribute__((address_space(1))) uint32_t*)aSrc(u, j),
                (__attribute__((address_space(3))) uint32_t*)(&Al[w_][b][j * 256]),
                16, 0, 0);
        }
    };
    auto wSrc = [&](int u) -> const uint32_t* {
        const int uc = (u < NU) ? u : (NU - 1);              // tail clamp
        const int sl = uc / VPS, v = uc % VPS;
        return wpack + (size_t)(sl * 256 + kp * VPS + v) * 1536 + lane * 4;
    };

    uint4 wbuf[2][6];

    // ---- prologue (order matters for the vmcnt ledger): W0(6), A0(2), A1(2)
    {
        const uint32_t* wp = wSrc(0);
#pragma unroll
        for (int f = 0; f < 6; ++f) wbuf[0][f] = *(const uint4*)(wp + f * 256);
        stageA(0, 0);
        stageA(1, 1);
    }

    const int r   = l31;
    const int sr  = (r & 3) ^ ((r >> 2) & 3);
    const int p0s = (kh * 2) ^ sr;          // physical slots of the two float4s
    const int p1s = (kh * 2 + 1) ^ sr;

    for (int uu = 0; uu < NU; uu += 4) {
#pragma unroll
        for (int pp = 0; pp < 4; ++pp) {    // all parities/buf indices static
            const int t   = uu + pp;
            const int cur = pp & 1;
            const int nxt = cur ^ 1;

            // (a) W(t+1) -> wbuf[nxt]: 6 dwordx4 from L2
            const uint32_t* wp = wSrc(t + 1);
#pragma unroll
            for (int f = 0; f < 6; ++f) wbuf[nxt][f] = *(const uint4*)(wp + f * 256);
            // (b) stage A(t+2): 2 gl_lds into buf (pp+2)&3
            stageA(t + 2, (pp + 2) & 3);
            // (c) ledger wait: keep newest 10 = A(t+1)2 + W(t+1)6 + A(t+2)2;
            //     retires A(t) and W(t). Memory clobber pins issue order.
            asm volatile("s_waitcnt vmcnt(10)" ::: "memory");

            // (d) A fragment from wave-private LDS (even-bank swizzled b128)
            const float* pA = &Al[w_][pp][0];
            const float4 a0 = *(const float4*)(pA + r * 16 + p0s * 4);
            const float4 a1 = *(const float4*)(pA + r * 16 + p1s * 4);

            // split to 3 bf16 fragments (truncation split, exact to 2^-24)
            uint32_t fa1[4], fa2[4], fa3[4];
            const float in[8] = { a0.x, a0.y, a0.z, a0.w, a1.x, a1.y, a1.z, a1.w };
#pragma unroll
            for (int j = 0; j < 4; ++j) {
                const float a = in[2 * j], b = in[2 * j + 1];
                const uint32_t ha = fbits(a) & 0xFFFF0000u, hb = fbits(b) & 0xFFFF0000u;
                fa1[j] = (ha >> 16) | hb;
                const float ra = a - bitsf(ha), rb = b - bitsf(hb);
                const uint32_t ha2 = fbits(ra) & 0xFFFF0000u, hb2 = fbits(rb) & 0xFFFF0000u;
                fa2[j] = (ha2 >> 16) | hb2;
                const float sa = ra - bitsf(ha2), sb = rb - bitsf(hb2);
                fa3[j] = (fbits(sa) >> 16) | (fbits(sb) & 0xFFFF0000u);
            }
            const bf16x8 a1f = asfrag(*(const uint4*)fa1);
            const bf16x8 a2f = asfrag(*(const uint4*)fa2);
            const bf16x8 a3f = asfrag(*(const uint4*)fa3);

#pragma unroll
            for (int nt = 0; nt < 2; ++nt) {
                const bf16x8 b1 = asfrag(wbuf[cur][nt * 3 + 0]);
                const bf16x8 b2 = asfrag(wbuf[cur][nt * 3 + 1]);
                const bf16x8 b3 = asfrag(wbuf[cur][nt * 3 + 2]);
                f32x16 c = acc[nt];          // ascending-magnitude product order
                c = __builtin_amdgcn_mfma_f32_32x32x16_bf16(a1f, b3, c, 0, 0, 0);
                c = __builtin_amdgcn_mfma_f32_32x32x16_bf16(a3f, b1, c, 0, 0, 0);
                c = __builtin_amdgcn_mfma_f32_32x32x16_bf16(a2f, b2, c, 0, 0, 0);
                c = __builtin_amdgcn_mfma_f32_32x32x16_bf16(a1f, b2, c, 0, 0, 0);
                c = __builtin_amdgcn_mfma_f32_32x32x16_bf16(a2f, b1, c, 0, 0, 0);
                c = __builtin_amdgcn_mfma_f32_32x32x16_bf16(a1f, b1, c, 0, 0, 0);
                acc[nt] = c;
            }

            // drain 64-k window into fp32 masters (static: pp==3)
            if (pp == 3) {
#pragma unroll
                for (int b = 0; b < 2; ++b)
#pragma unroll
                    for (int i = 0; i < 16; ++i) { macc[b][i] += acc[b][i]; acc[b][i] = 0.f; }
            }
        }
    }

    // drain all in-flight loads (tail trash) before LDS goes away / stores
    asm volatile("s_waitcnt vmcnt(0)" ::: "memory");

    // write plane; C/D layout (HW-verified): col=lane&31, row=(r&3)+8*(r>>2)+4*(lane>>5)
    float* __restrict__ out = part + (size_t)blockIdx.y * M_TOTAL * EXP;
#pragma unroll
    for (int nt = 0; nt < 2; ++nt)
#pragma unroll
        for (int rr = 0; rr < 16; ++rr) {
            const int orow = rowBase + (rr & 3) + 8 * (rr >> 2) + 4 * kh;
            out[(size_t)orow * EXP + nt * 32 + l31] = macc[nt][rr];
        }
}

// one wave per row: logits = f64 sum of planes; top-2 (jax tie-break: lower index
// wins); gates = 2-logit softmax == renormalized full softmax.
__global__ __launch_bounds__(256) void topk_epilogue3(
    const float* __restrict__ part, const int nplanes, float* __restrict__ outv)
{
    const int tid  = threadIdx.x;
    const int lane = tid & 63;
    const int row  = blockIdx.x * 4 + (tid >> 6);

    double sd = 0.0;
    for (int p = 0; p < nplanes; ++p)
        sd += (double)part[((size_t)p * M_TOTAL + row) * EXP + lane];
    const float logit = (float)sd;

    float v = logit; int idx = lane;
#pragma unroll
    for (int off = 32; off >= 1; off >>= 1) {
        const float vo = __shfl_xor(v, off, 64);
        const int   io = __shfl_xor(idx, off, 64);
        if (vo > v || (vo == v && io < idx)) { v = vo; idx = io; }
    }
    const float v1 = v; const int i1 = idx;

    float v2 = (lane == i1) ? -INFINITY : logit; int idx2 = lane;
#pragma unroll
    for (int off = 32; off >= 1; off >>= 1) {
        const float vo = __shfl_xor(v2, off, 64);
        const int   io = __shfl_xor(idx2, off, 64);
        if (vo > v2 || (vo == v2 && io < idx2)) { v2 = vo; idx2 = io; }
    }

    if (lane == 0) {
        const float e2 = expf(v2 - v1);       // <= 1
        const float g1 = 1.0f / (1.0f + e2);
        const float g2 = e2 * g1;
        outv[(size_t)row * 2 + 0] = g1;
        outv[(size_t)row * 2 + 1] = g2;
        outv[(size_t)2 * M_TOTAL + row * 2 + 0] = (float)i1;
        outv[(size_t)2 * M_TOTAL + row * 2 + 1] = (float)idx2;
    }
}

extern "C" void kernel_launch(void* const* d_in, const int* in_sizes, int n_in,
                              void* d_out, int out_size, void* d_ws, size_t ws_size,
                              hipStream_t stream)
{
    const float* x     = (const float*)d_in[0];
    const float* noise = (const float*)d_in[1];
    const float* w     = (const float*)d_in[2];
    const float* nw    = (const float*)d_in[3];
    // d_in[4] = top_k (==2), compile-time assumed

    const size_t plane_bytes = (size_t)M_TOTAL * EXP * sizeof(float);
    const size_t wpack_bytes = (size_t)786432 * 4;
    float* part = (float*)d_ws;

    if (ws_size >= 8 * plane_bytes + wpack_bytes) {
        uint32_t* wpack = (uint32_t*)((char*)d_ws + 8 * plane_bytes);
        wpack_prep<<<3072, 256, 0, stream>>>(w, nw, wpack);
        router_mfma6<8><<<dim3(128, 8), 256, 0, stream>>>(x, noise, wpack, part);
        topk_epilogue3<<<M_TOTAL / 4, 256, 0, stream>>>(part, 8, (float*)d_out);
    } else if (ws_size >= 4 * plane_bytes + wpack_bytes) {
        uint32_t* wpack = (uint32_t*)((char*)d_ws + 4 * plane_bytes);
        wpack_prep<<<3072, 256, 0, stream>>>(w, nw, wpack);
        router_mfma6<4><<<dim3(128, 4), 256, 0, stream>>>(x, noise, wpack, part);
        topk_epilogue3<<<M_TOTAL / 4, 256, 0, stream>>>(part, 4, (float*)d_out);
    } else {
        uint32_t* wpack = (uint32_t*)((char*)d_ws + 2 * plane_bytes);
        wpack_prep<<<3072, 256, 0, stream>>>(w, nw, wpack);
        router_mfma6<2><<<dim3(128, 2), 256, 0, stream>>>(x, noise, wpack, part);
        topk_epilogue3<<<M_TOTAL / 4, 256, 0, stream>>>(part, 2, (float*)d_out);
    }
}

// Round 10
// 179.182 us; speedup vs baseline: 1.3519x; 1.2164x over previous
//
#include <hip/hip_runtime.h>
#include <math.h>
#include <stdint.h>

#define M_TOTAL 16384
#define DDIM    4096
#define EXP     64

typedef __attribute__((ext_vector_type(8)))  short bf16x8;
typedef __attribute__((ext_vector_type(16))) float f32x16;

__device__ inline uint32_t fbits(float f){ union{float f;uint32_t u;}c; c.f=f; return c.u; }
__device__ inline float    bitsf(uint32_t u){ union{uint32_t u;float f;}c; c.u=u; return c.f; }
__device__ inline bf16x8   asfrag(uint4 t){ return __builtin_bit_cast(bf16x8, t); }

// ---------------------------------------------------------------------------
// W pre-pack: split w/nw into 3 bf16 planes (truncation split, exact to 2^-24)
// stored in MFMA-B-fragment-linear order:
//   word index = (((s*256 + kt)*2 + nt)*3 + pl)*256 + lane*4 + j
//   lane = (e&31) + 32*((k>>3)&1), word j holds k-elems 2j,2j+1
// ---------------------------------------------------------------------------
__global__ __launch_bounds__(256) void wpack_prep(
    const float* __restrict__ w, const float* __restrict__ nw,
    uint32_t* __restrict__ wpack)
{
    const int t = blockIdx.x * 256 + threadIdx.x;     // 786432 words total
    const int jw   = t & 3;
    const int lane = (t >> 2) & 63;
    const int rest = t >> 8;                          // ((s*256+kt)*2+nt)*3+pl
    const int pl   = rest % 3;
    const int r2   = rest / 3;
    const int nt   = r2 & 1;
    const int kt   = (r2 >> 1) & 255;
    const int s    = r2 >> 9;

    const int k0 = kt * 16 + (lane >> 5) * 8 + 2 * jw;
    const int e  = nt * 32 + (lane & 31);
    const float* __restrict__ src = s ? nw : w;
    float f0 = src[(size_t)k0 * EXP + e];
    float f1 = src[(size_t)(k0 + 1) * EXP + e];
    uint32_t u0 = fbits(f0), u1 = fbits(f1);
    for (int l = 0; l < pl; ++l) {                    // peel to level pl
        f0 -= bitsf(u0 & 0xFFFF0000u);
        f1 -= bitsf(u1 & 0xFFFF0000u);
        u0 = fbits(f0); u1 = fbits(f1);
    }
    wpack[t] = (u0 >> 16) | (u1 & 0xFFFF0000u);       // [lo=elem2j, hi=elem2j+1]
}

// ---------------------------------------------------------------------------
// MFMA GEMM, wave-private pipeline with 256B-contiguous A staging:
// part[kp][row][e] = sum over k-plane of (x@w + noise@nw)
// Wave = 32 rows x 64 experts. A: 64k-wide chunks (32 rows x 256 B), staged
// by global_load_lds instrs of 1 KB = 4 rows x 256 B contiguous (2x128B lines
// per row run -> big DRAM transactions). Slot permutation slot=(kq^u+2q)&15
// applied on SOURCE (linear LDS dest) and identically on the ds_read side:
// perfect-minimal bank pattern (8 lanes/16B-slot), no padding, LDS = 64 KB.
// ZERO barriers; counted vmcnt ledger (8 vmem ops/kstep uniform).
// ---------------------------------------------------------------------------
template<int KSPLIT>
__global__ __launch_bounds__(256, 2) void router_mfma7(
    const float* __restrict__ x, const float* __restrict__ noise,
    const uint32_t* __restrict__ wpack, float* __restrict__ part)
{
    constexpr int KRANGE = DDIM / KSPLIT;   // k per plane
    constexpr int VPS    = KRANGE / 16;     // ksteps per slice
    constexpr int NU     = 2 * VPS;         // ksteps total
    constexpr int CPS    = KRANGE / 64;     // 64k-chunks per slice
    constexpr int NC     = 2 * CPS;         // chunks total (= NU/4)

    __shared__ float Alf[4][2][2048];       // [wave][buf][32 rows x 64 k] = 64 KB

    const int tid  = threadIdx.x;
    const int w_   = tid >> 6;
    const int lane = tid & 63;
    const int l31  = lane & 31;
    const int kh   = lane >> 5;             // k-half of the fragment

    const int rowBase = blockIdx.x * 128 + w_ * 32;
    const int kp      = blockIdx.y;

    // ---- stage-side lane decomposition: instr j covers rows 4j..4j+3;
    //      16 lanes per row read its 256 B run, slot-permuted on the source
    const int su = lane >> 4;               // row-in-quad (0..3)
    const int ss = lane & 15;               // physical 16B slot (dest linear)

    // ---- read-side per-phase LDS offsets (floats), all static per phase:
    //      slot(kq) = ((kq ^ u) + 2q) & 15,  q=row>>2, u=row&3
    const int q = l31 >> 2, u = l31 & 3;
    int o0[4], o1[4];
#pragma unroll
    for (int p = 0; p < 4; ++p) {
        const int s0 = (((4 * p + 2 * kh)     ^ u) + 2 * q) & 15;
        const int s1 = (((4 * p + 2 * kh + 1) ^ u) + 2 * q) & 15;
        o0[p] = q * 256 + u * 64 + s0 * 4;
        o1[p] = q * 256 + u * 64 + s1 * 4;
    }

    f32x16 acc[2], macc[2];
#pragma unroll
    for (int b = 0; b < 2; ++b)
#pragma unroll
        for (int i = 0; i < 16; ++i) { acc[b][i] = 0.f; macc[b][i] = 0.f; }

    auto stageA = [&](int c1, int bufn, int j) {  // 1 instr: 4 rows x 256 B
        const int cc = (c1 < NC) ? c1 : (NC - 1);          // tail clamp
        const int sl = cc / CPS, ck = cc % CPS;
        const float* __restrict__ base = sl ? noise : x;
        const int kq = ((ss - 2 * j) & 15) ^ su;           // logical k-quad
        const float* src = base + (size_t)(rowBase + 4 * j + su) * DDIM
                         + kp * KRANGE + ck * 64 + kq * 4;
        __builtin_amdgcn_global_load_lds(
            (const __attribute__((address_space(1))) uint32_t*)src,
            (__attribute__((address_space(3))) uint32_t*)(&Alf[w_][bufn][j * 256]),
            16, 0, 0);
    };
    auto wSrc = [&](int t) -> const uint32_t* {
        const int tc = (t < NU) ? t : (NU - 1);            // tail clamp
        const int sl = tc / VPS, v = tc % VPS;
        return wpack + (size_t)(sl * 256 + kp * VPS + v) * 1536 + lane * 4;
    };

    uint4 wbuf[2][6];

    // ---- prologue (ledger order): W(0) x6, chunk0 stages x8
    {
        const uint32_t* wp = wSrc(0);
#pragma unroll
        for (int f = 0; f < 6; ++f) wbuf[0][f] = *(const uint4*)(wp + f * 256);
#pragma unroll
        for (int j = 0; j < 8; ++j) stageA(0, 0, j);
    }

    for (int c = 0; c < NC; ++c) {
        const int bufc = c & 1;
#pragma unroll
        for (int p = 0; p < 4; ++p) {       // kstep t = 4c+p; W parity = p&1
            const int t = c * 4 + p;

            // (a) W(t+1) -> wbuf[(p+1)&1]: 6 dwordx4 from L2-resident wpack
            const uint32_t* wp = wSrc(t + 1);
#pragma unroll
            for (int f = 0; f < 6; ++f) wbuf[(p + 1) & 1][f] = *(const uint4*)(wp + f * 256);
            // (b) 2 stages of chunk c+1 into the other buffer
            stageA(c + 1, bufc ^ 1, 2 * p);
            stageA(c + 1, bufc ^ 1, 2 * p + 1);
            // (c) ledger: p==0 keeps {W(t+1),2 stages}=8 (retires W(t) + all of
            //     chunk c's stages); p>0 keeps +2 older in-flight stages = 10.
            if (p == 0) asm volatile("s_waitcnt vmcnt(8)"  ::: "memory");
            else        asm volatile("s_waitcnt vmcnt(10)" ::: "memory");

            // (d) A fragment from wave-private LDS (perfect-min bank pattern)
            const float4 a0 = *(const float4*)&Alf[w_][bufc][o0[p]];
            const float4 a1 = *(const float4*)&Alf[w_][bufc][o1[p]];

            // split to 3 bf16 fragments (truncation split, exact to 2^-24)
            uint32_t fa1[4], fa2[4], fa3[4];
            const float in[8] = { a0.x, a0.y, a0.z, a0.w, a1.x, a1.y, a1.z, a1.w };
#pragma unroll
            for (int j = 0; j < 4; ++j) {
                const float a = in[2 * j], b = in[2 * j + 1];
                const uint32_t ha = fbits(a) & 0xFFFF0000u, hb = fbits(b) & 0xFFFF0000u;
                fa1[j] = (ha >> 16) | hb;
                const float ra = a - bitsf(ha), rb = b - bitsf(hb);
                const uint32_t ha2 = fbits(ra) & 0xFFFF0000u, hb2 = fbits(rb) & 0xFFFF0000u;
                fa2[j] = (ha2 >> 16) | hb2;
                const float sa = ra - bitsf(ha2), sb = rb - bitsf(hb2);
                fa3[j] = (fbits(sa) >> 16) | (fbits(sb) & 0xFFFF0000u);
            }
            const bf16x8 a1f = asfrag(*(const uint4*)fa1);
            const bf16x8 a2f = asfrag(*(const uint4*)fa2);
            const bf16x8 a3f = asfrag(*(const uint4*)fa3);

#pragma unroll
            for (int nt = 0; nt < 2; ++nt) {
                const bf16x8 b1 = asfrag(wbuf[p & 1][nt * 3 + 0]);
                const bf16x8 b2 = asfrag(wbuf[p & 1][nt * 3 + 1]);
                const bf16x8 b3 = asfrag(wbuf[p & 1][nt * 3 + 2]);
                f32x16 cc = acc[nt];         // ascending-magnitude product order
                cc = __builtin_amdgcn_mfma_f32_32x32x16_bf16(a1f, b3, cc, 0, 0, 0);
                cc = __builtin_amdgcn_mfma_f32_32x32x16_bf16(a3f, b1, cc, 0, 0, 0);
                cc = __builtin_amdgcn_mfma_f32_32x32x16_bf16(a2f, b2, cc, 0, 0, 0);
                cc = __builtin_amdgcn_mfma_f32_32x32x16_bf16(a1f, b2, cc, 0, 0, 0);
                cc = __builtin_amdgcn_mfma_f32_32x32x16_bf16(a2f, b1, cc, 0, 0, 0);
                cc = __builtin_amdgcn_mfma_f32_32x32x16_bf16(a1f, b1, cc, 0, 0, 0);
                acc[nt] = cc;
            }

            // drain 64-k window (one chunk) into fp32 masters
            if (p == 3) {
#pragma unroll
                for (int b = 0; b < 2; ++b)
#pragma unroll
                    for (int i = 0; i < 16; ++i) { macc[b][i] += acc[b][i]; acc[b][i] = 0.f; }
            }
        }
    }

    // drain tail-clamped in-flight loads before LDS lifetime ends
    asm volatile("s_waitcnt vmcnt(0)" ::: "memory");

    // write plane; C/D layout (HW-verified): col=lane&31, row=(r&3)+8*(r>>2)+4*(lane>>5)
    float* __restrict__ out = part + (size_t)blockIdx.y * M_TOTAL * EXP;
#pragma unroll
    for (int nt = 0; nt < 2; ++nt)
#pragma unroll
        for (int rr = 0; rr < 16; ++rr) {
            const int orow = rowBase + (rr & 3) + 8 * (rr >> 2) + 4 * kh;
            out[(size_t)orow * EXP + nt * 32 + l31] = macc[nt][rr];
        }
}

// one wave per row: logits = f64 sum of planes; top-2 (jax tie-break: lower index
// wins); gates = 2-logit softmax == renormalized full softmax.
__global__ __launch_bounds__(256) void topk_epilogue3(
    const float* __restrict__ part, const int nplanes, float* __restrict__ outv)
{
    const int tid  = threadIdx.x;
    const int lane = tid & 63;
    const int row  = blockIdx.x * 4 + (tid >> 6);

    double sd = 0.0;
    for (int p = 0; p < nplanes; ++p)
        sd += (double)part[((size_t)p * M_TOTAL + row) * EXP + lane];
    const float logit = (float)sd;

    float v = logit; int idx = lane;
#pragma unroll
    for (int off = 32; off >= 1; off >>= 1) {
        const float vo = __shfl_xor(v, off, 64);
        const int   io = __shfl_xor(idx, off, 64);
        if (vo > v || (vo == v && io < idx)) { v = vo; idx = io; }
    }
    const float v1 = v; const int i1 = idx;

    float v2 = (lane == i1) ? -INFINITY : logit; int idx2 = lane;
#pragma unroll
    for (int off = 32; off >= 1; off >>= 1) {
        const float vo = __shfl_xor(v2, off, 64);
        const int   io = __shfl_xor(idx2, off, 64);
        if (vo > v2 || (vo == v2 && io < idx2)) { v2 = vo; idx2 = io; }
    }

    if (lane == 0) {
        const float e2 = expf(v2 - v1);       // <= 1
        const float g1 = 1.0f / (1.0f + e2);
        const float g2 = e2 * g1;
        outv[(size_t)row * 2 + 0] = g1;
        outv[(size_t)row * 2 + 1] = g2;
        outv[(size_t)2 * M_TOTAL + row * 2 + 0] = (float)i1;
        outv[(size_t)2 * M_TOTAL + row * 2 + 1] = (float)idx2;
    }
}

extern "C" void kernel_launch(void* const* d_in, const int* in_sizes, int n_in,
                              void* d_out, int out_size, void* d_ws, size_t ws_size,
                              hipStream_t stream)
{
    const float* x     = (const float*)d_in[0];
    const float* noise = (const float*)d_in[1];
    const float* w     = (const float*)d_in[2];
    const float* nw    = (const float*)d_in[3];
    // d_in[4] = top_k (==2), compile-time assumed

    const size_t plane_bytes = (size_t)M_TOTAL * EXP * sizeof(float);
    const size_t wpack_bytes = (size_t)786432 * 4;
    float* part = (float*)d_ws;

    if (ws_size >= 8 * plane_bytes + wpack_bytes) {
        uint32_t* wpack = (uint32_t*)((char*)d_ws + 8 * plane_bytes);
        wpack_prep<<<3072, 256, 0, stream>>>(w, nw, wpack);
        router_mfma7<8><<<dim3(128, 8), 256, 0, stream>>>(x, noise, wpack, part);
        topk_epilogue3<<<M_TOTAL / 4, 256, 0, stream>>>(part, 8, (float*)d_out);
    } else if (ws_size >= 4 * plane_bytes + wpack_bytes) {
        uint32_t* wpack = (uint32_t*)((char*)d_ws + 4 * plane_bytes);
        wpack_prep<<<3072, 256, 0, stream>>>(w, nw, wpack);
        router_mfma7<4><<<dim3(128, 4), 256, 0, stream>>>(x, noise, wpack, part);
        topk_epilogue3<<<M_TOTAL / 4, 256, 0, stream>>>(part, 4, (float*)d_out);
    } else {
        uint32_t* wpack = (uint32_t*)((char*)d_ws + 2 * plane_bytes);
        wpack_prep<<<3072, 256, 0, stream>>>(w, nw, wpack);
        router_mfma7<2><<<dim3(128, 2), 256, 0, stream>>>(x, noise, wpack, part);
        topk_epilogue3<<<M_TOTAL / 4, 256, 0, stream>>>(part, 2, (float*)d_out);
    }
}